// Round 1
// baseline (81649.512 us; speedup 1.0000x reference)
//
#include <hip/hip_runtime.h>

// GRU recurrence, T=32768, I=H=512.
// Persistent 32-block kernel; weights register-resident; h exchanged per step
// through tag-packed u64 agent-scope atomics in d_ws (16 KB ring).

#define T_STEPS 32768
#define HID     512
#define NBLK    32      // blocks; each owns HS hidden units
#define HS      16      // hidden units per block
#define RING    4       // h-ring slots (skew bounded by 1; 4 for paranoia)
#define SPIN_CAP (1u << 18)

// acc += W[g][kk*4 + m] * v[m], all indices compile-time after unroll
#define FMA4(acc, W, g, vv)                                                   \
    acc = fmaf(W[g][(kk << 2) + 0], vv.x, acc);                               \
    acc = fmaf(W[g][(kk << 2) + 1], vv.y, acc);                               \
    acc = fmaf(W[g][(kk << 2) + 2], vv.z, acc);                               \
    acc = fmaf(W[g][(kk << 2) + 3], vv.w, acc);

__global__ __launch_bounds__(256, 1) void gru_persistent(
    const float* __restrict__ xs,      // (T, 512)
    const float* __restrict__ w_ih,    // (1536, 512)
    const float* __restrict__ w_hh,    // (1536, 512)
    const float* __restrict__ bias,    // (1536,)
    const float* __restrict__ bias_n,  // (512,)
    float* __restrict__ out,           // (T, 512)
    unsigned long long* __restrict__ hbuf)  // RING*512 packed (tag<<32 | f32)
{
    const int b    = blockIdx.x;
    const int tid  = threadIdx.x;
    const int wave = tid >> 6;
    const int lane = tid & 63;
    const int jl   = (wave << 2) + (lane >> 4);  // 0..15 : local hidden idx
    const int sub  = lane & 15;                  // 0..15 : 32-col chunk
    const int j    = b * HS + jl;                // global hidden idx
    const int c0   = sub << 5;                   // column base

    __shared__ float x_s[2][HID];
    __shared__ float h_s[HID];

    // ---- preload weights into registers, rotated so LDS reads stagger banks
    float wih[3][32], whh[3][32];
#pragma unroll
    for (int g = 0; g < 3; ++g) {
        const float* rih = w_ih + (size_t)(g * HID + j) * HID + c0;
        const float* rhh = w_hh + (size_t)(g * HID + j) * HID + c0;
#pragma unroll
        for (int kk = 0; kk < 8; ++kk) {
            const int c = ((sub + kk) & 7) << 2;   // rotated col offset
            const float4 a  = *(const float4*)(rih + c);
            const float4 bb = *(const float4*)(rhh + c);
            wih[g][(kk << 2) + 0] = a.x;  wih[g][(kk << 2) + 1] = a.y;
            wih[g][(kk << 2) + 2] = a.z;  wih[g][(kk << 2) + 3] = a.w;
            whh[g][(kk << 2) + 0] = bb.x; whh[g][(kk << 2) + 1] = bb.y;
            whh[g][(kk << 2) + 2] = bb.z; whh[g][(kk << 2) + 3] = bb.w;
        }
    }
    const float b_r  = bias[j];
    const float b_z  = bias[HID + j];
    const float b_nn = bias[2 * HID + j];
    const float bn2  = bias_n[j];

    // ---- x staging: 2 floats per thread, double-buffered LDS
    const int xi = tid << 1;
    float2 xreg = *(const float2*)(xs + xi);           // x_0
    x_s[0][xi] = xreg.x; x_s[0][xi + 1] = xreg.y;
    xreg = *(const float2*)(xs + HID + xi);            // x_1 (staged at t=0)
    __syncthreads();

    float hprev = 0.f;       // owner lane's own h[j]
    bool  dead  = false;     // anti-hang insurance

    for (int t = 0; t < T_STEPS; ++t) {
        // ---- x-dot: independent of h, overlaps the spin window -------------
        float ar = 0.f, az = 0.f, an = 0.f;
        const float* xb = x_s[t & 1];
#pragma unroll
        for (int kk = 0; kk < 8; ++kk) {
            const int c = c0 + (((sub + kk) & 7) << 2);
            const float4 xv = *(const float4*)(xb + c);
            FMA4(ar, wih, 0, xv)
            FMA4(az, wih, 1, xv)
            FMA4(an, wih, 2, xv)
        }

        // ---- obtain h_{t-1}: tag-packed spin (tag == t) ---------------------
        if (t > 0) {
            const unsigned long long* src =
                hbuf + ((size_t)((t - 1) & (RING - 1)) * HID) + xi;
            const unsigned int tag = (unsigned int)t;
            unsigned long long v0 = 0, v1 = 0;
            if (!dead) {
                unsigned int it = 0;
                do {
                    v0 = __hip_atomic_load(src, __ATOMIC_RELAXED,
                                           __HIP_MEMORY_SCOPE_AGENT);
                } while ((unsigned int)(v0 >> 32) != tag && ++it < SPIN_CAP);
                if (it >= SPIN_CAP) dead = true;
                it = 0;
                do {
                    v1 = __hip_atomic_load(src + 1, __ATOMIC_RELAXED,
                                           __HIP_MEMORY_SCOPE_AGENT);
                } while ((unsigned int)(v1 >> 32) != tag && ++it < SPIN_CAP);
                if (it >= SPIN_CAP) dead = true;
            }
            h_s[xi]     = __uint_as_float((unsigned int)v0);
            h_s[xi + 1] = __uint_as_float((unsigned int)v1);
        } else {
            h_s[xi] = 0.f; h_s[xi + 1] = 0.f;
        }
        __syncthreads();

        // ---- h-dot ----------------------------------------------------------
        float hr = 0.f, hz = 0.f, hn = 0.f;
#pragma unroll
        for (int kk = 0; kk < 8; ++kk) {
            const int c = c0 + (((sub + kk) & 7) << 2);
            const float4 hv = *(const float4*)(h_s + c);
            FMA4(hr, whh, 0, hv)
            FMA4(hz, whh, 1, hv)
            FMA4(hn, whh, 2, hv)
        }

        // ---- 16-lane butterfly reduce (r, z, x-n, h-n) ----------------------
        float s1 = ar + hr, s2 = az + hz, s3 = an, s4 = hn;
#pragma unroll
        for (int m = 1; m < 16; m <<= 1) {
            s1 += __shfl_xor(s1, m);
            s2 += __shfl_xor(s2, m);
            s3 += __shfl_xor(s3, m);
            s4 += __shfl_xor(s4, m);
        }

        // ---- gates + publish (owner lanes) ----------------------------------
        if (sub == 0) {
            const float r = 1.f / (1.f + __expf(-(s1 + b_r)));
            const float z = 1.f / (1.f + __expf(-(s2 + b_z)));
            const float n = tanhf(s3 + b_nn + r * (s4 + bn2));
            const float h = n + z * (hprev - n);
            hprev = h;
            out[(size_t)t * HID + j] = h;
            const unsigned long long pv =
                ((unsigned long long)(unsigned int)(t + 1) << 32) |
                (unsigned long long)__float_as_uint(h);
            __hip_atomic_store(hbuf + ((size_t)(t & (RING - 1)) * HID) + j, pv,
                               __ATOMIC_RELAXED, __HIP_MEMORY_SCOPE_AGENT);
        }

        // ---- stage x_{t+1}, prefetch x_{t+2} --------------------------------
        x_s[(t + 1) & 1][xi]     = xreg.x;
        x_s[(t + 1) & 1][xi + 1] = xreg.y;
        {
            const int tn = (t + 2 < T_STEPS) ? (t + 2) : (T_STEPS - 1);
            xreg = *(const float2*)(xs + (size_t)tn * HID + xi);
        }
        __syncthreads();
    }
}

extern "C" void kernel_launch(void* const* d_in, const int* in_sizes, int n_in,
                              void* d_out, int out_size, void* d_ws, size_t ws_size,
                              hipStream_t stream) {
    const float* xs     = (const float*)d_in[0];
    const float* w_ih   = (const float*)d_in[1];
    const float* w_hh   = (const float*)d_in[2];
    const float* bias   = (const float*)d_in[3];
    const float* bias_n = (const float*)d_in[4];
    float* out = (float*)d_out;
    unsigned long long* hbuf = (unsigned long long*)d_ws;

    // clear the tag ring (poison 0xAA.. or stale tags must never match)
    hipMemsetAsync(d_ws, 0, (size_t)RING * HID * sizeof(unsigned long long), stream);

    hipLaunchKernelGGL(gru_persistent, dim3(NBLK), dim3(256), 0, stream,
                       xs, w_ih, w_hh, bias, bias_n, out, hbuf);
}